// Round 3
// baseline (781.422 us; speedup 1.0000x reference)
//
#include <hip/hip_runtime.h>
#include <math.h>

#define NB 4
#define T 65536
#define TIN 8192
#define LL 256
#define KCL 6144   // per-layer kernel channels = 32*64*3

__device__ __forceinline__ float lrelu_f(float v) { return v >= 0.f ? v : 0.2f * v; }

// ---------------- prep1: weight transposes for divergent per-lane loads ----------------
// trb  [conv 6][c*3+k 192][oc 64]   from rb_w1/rb_w2 [i][oc][c][k]
// tkpin[(cin*5+k) 500][oc 64]       from kp_in_w [oc][cin][k]
__global__ void __launch_bounds__(256) prep1(
    const float* __restrict__ rb_w1, const float* __restrict__ rb_w2,
    const float* __restrict__ kp_in_w,
    float* __restrict__ trb, float* __restrict__ tkpin) {
  __shared__ float t[64][193];
  const int bid = blockIdx.x, tid = threadIdx.x;
  if (bid < 6) {
    int i = bid >> 1, which = bid & 1;
    const float* src = (which ? rb_w2 : rb_w1) + (size_t)i * 12288;
    float* dst = trb + (size_t)bid * 12288;
    for (int idx = tid; idx < 64 * 192; idx += 256) {
      int o = idx / 192, J = idx % 192;
      t[o][J] = src[(size_t)o * 192 + J];
    }
    __syncthreads();
    for (int idx = tid; idx < 64 * 192; idx += 256) {
      int J = idx >> 6, o = idx & 63;
      dst[(size_t)J * 64 + o] = t[o][J];
    }
  } else {
    for (int idx = tid; idx < 500 * 64; idx += 256) {
      int row = idx >> 6, o = idx & 63;
      tkpin[idx] = kp_in_w[o * 500 + row];
    }
  }
}

// ---------------- phase1: trunk (64 blocks, first) + convt (264 blocks) ----------------
// trunk: 256 independent single-wave units (4 per block, waves 4..7 exit).
// Each unit computes ALL 64 channels x 16 halo cols for its 4 output cols.
// Weights: per-lane divergent global loads (VMEM). x: per-unit LDS, in-order DS.
union Phase1LDS {
  struct { float xs[32][264]; float wm[64][128]; } cvt;     // 66.6 KB
  struct { float hs[4][64][20]; float xsp[4][100][24]; } trk; // 58.9 KB
};

__global__ void __launch_bounds__(512) phase1(
    const float* __restrict__ x, const float* __restrict__ cw,
    const float* __restrict__ cbias, float* __restrict__ hout,
    const float* __restrict__ spec,
    const float* __restrict__ tkpin, const float* __restrict__ kp_in_b,
    const float* __restrict__ trb, const float* __restrict__ rb_b1,
    const float* __restrict__ rb_b2, float* __restrict__ kp_h) {
  __shared__ Phase1LDS sm;
  const int bid = blockIdx.x;
  const int tid = threadIdx.x;
  const int lane = tid & 63, wv = tid >> 6;

  if (bid < 64) {
    // ================= trunk role =================
    if (wv >= 4) return;                 // 4 units per block, 1 wave/SIMD
    const int unit = bid * 4 + wv;       // 0..255
    const int b = unit >> 6;             // batch
    const int chunk = unit & 63;         // 64 chunks x 4 cols = 256 cols
    const int l0 = chunk * 4;
    const int og = lane >> 1;            // 0..31 -> oc pair
    const int colg = lane & 1;           // 0..1  -> 8 cols each
    const int colg8 = colg * 8;
    const int obase = og * 2;            // 2 output channels per lane (covers all 64)
    float (*hsu)[20] = sm.trk.hs[wv];
    float (*xspu)[24] = sm.trk.xsp[wv];

    // zero-init hs (idx 0 and 17..19 stay 0 = halo padding)
    for (int i = lane; i < 64 * 20; i += 64) ((float*)hsu)[i] = 0.f;

    // stage ALL spec channels: xsp[cin][cx], cx = labs-(l0-8), window 20 (+4 pad)
    for (int i = lane; i < 100 * 24; i += 64) {
      int cin = i / 24, cx = i - cin * 24;
      float v = 0.f;
      if (cx < 20) {
        int labs = l0 - 8 + cx;
        if (labs >= 0 && labs < 256)
          v = spec[((size_t)b * 100 + cin) * LL + labs];
      }
      xspu[cin][cx] = v;
    }

    // ---- kp_in (k=5, pad 2): compute rel 0..15 (labs = l0-6+rel) ----
    float hcur[2][8];
    {
      float acc[2][8];
      float2 bb = *(const float2*)(kp_in_b + obase);
#pragma unroll
      for (int q = 0; q < 8; ++q) { acc[0][q] = bb.x; acc[1][q] = bb.y; }
#pragma unroll 2
      for (int cin = 0; cin < 100; ++cin) {
        float x12[12];
        *(float4*)&x12[0] = *(const float4*)&xspu[cin][colg8];
        *(float4*)&x12[4] = *(const float4*)&xspu[cin][colg8 + 4];
        *(float4*)&x12[8] = *(const float4*)&xspu[cin][colg8 + 8];
        const float* wp = tkpin + (size_t)(cin * 5) * 64 + obase;
#pragma unroll
        for (int k = 0; k < 5; ++k) {
          float2 w = *(const float2*)(wp + k * 64);
#pragma unroll
          for (int q = 0; q < 8; ++q) {
            acc[0][q] += x12[q + k] * w.x;
            acc[1][q] += x12[q + k] * w.y;
          }
        }
      }
#pragma unroll
      for (int oi = 0; oi < 2; ++oi)
#pragma unroll
        for (int q = 0; q < 8; ++q) {
          int rel = colg8 + q, labs = l0 - 6 + rel;
          float v = (labs >= 0 && labs < 256) ? acc[oi][q] : 0.f;
          hcur[oi][q] = v;
          hsu[obase + oi][rel + 1] = v;
        }
    }

    // ---- 6 convs (3 residual blocks); output valid rel in [cv+1, 15-cv) ----
    for (int cv = 0; cv < 6; ++cv) {
      const float* wb = trb + (size_t)cv * 12288;
      const float* bp = (cv & 1) ? rb_b2 + (cv >> 1) * 64 : rb_b1 + (cv >> 1) * 64;
      float2 bb = *(const float2*)(bp + obase);
      float acc[2][8];
#pragma unroll
      for (int q = 0; q < 8; ++q) { acc[0][q] = bb.x; acc[1][q] = bb.y; }
#pragma unroll 2
      for (int c = 0; c < 64; ++c) {
        float x10[10];
        *(float4*)&x10[0] = *(const float4*)&hsu[c][colg8];
        *(float4*)&x10[4] = *(const float4*)&hsu[c][colg8 + 4];
        *(float2*)&x10[8] = *(const float2*)&hsu[c][colg8 + 8];
        const float* wp = wb + (size_t)(c * 192) + obase;
        float2 w0 = *(const float2*)(wp);
        float2 w1 = *(const float2*)(wp + 64);
        float2 w2 = *(const float2*)(wp + 128);
#pragma unroll
        for (int q = 0; q < 8; ++q) {
          acc[0][q] += x10[q] * w0.x + x10[q + 1] * w1.x + x10[q + 2] * w2.x;
          acc[1][q] += x10[q] * w0.y + x10[q + 1] * w1.y + x10[q + 2] * w2.y;
        }
      }
      const int lo = cv + 1, hi = 15 - cv;
#pragma unroll
      for (int oi = 0; oi < 2; ++oi)
#pragma unroll
        for (int q = 0; q < 8; ++q) {
          int rel = colg8 + q, labs = l0 - 6 + rel;
          float v = lrelu_f(acc[oi][q]);
          if (cv & 1) v += hcur[oi][q];
          bool ok = (rel >= lo) && (rel < hi) && (labs >= 0) && (labs < 256);
          v = ok ? v : 0.f;
          if (cv & 1) hcur[oi][q] = v;
          if (cv < 5) hsu[obase + oi][rel + 1] = v;
        }
    }

    // ---- write kp_h: final valid rel in [6,10) -> labs l0..l0+3 ----
#pragma unroll
    for (int oi = 0; oi < 2; ++oi)
#pragma unroll
      for (int q = 0; q < 8; ++q) {
        int rel = colg8 + q;
        if (rel >= 6 && rel < 10)
          kp_h[((size_t)b * 64 + obase + oi) * LL + l0 + rel - 6] = hcur[oi][q];
      }
    return;
  }

  // ================= convt role (round-0, known good) =================
  const int cb = bid - 64;
  const int bx = cb % 33;
  const int rr = cb / 33;
  const int mtp = rr & 1;
  const int b = rr >> 1;
  const int s0base = bx * 256;
  float (*xs)[264] = sm.cvt.xs;
  float (*wm)[128] = sm.cvt.wm;

  const float* xb = x + (size_t)b * 32 * TIN;
  for (int idx = tid; idx < 32 * 64; idx += 512) {
    int c = idx >> 6, q = idx & 63;
    int p = s0base + q * 4;
    float4 v = (p + 3 < TIN) ? *(const float4*)(xb + c * TIN + p)
                             : make_float4(0.f, 0.f, 0.f, 0.f);
    *(float4*)&xs[c][4 + 4 * q] = v;
  }
  if (tid < 32) {
    int p = s0base - 1;
    xs[tid][3] = (p >= 0) ? xb[tid * TIN + p] : 0.f;
  }
  for (int idx = tid; idx < 8192; idx += 512) {
    int i = idx >> 7, mm = idx & 127;
    int oo = mtp * 16 + (mm >> 3), k0 = mm & 7;
    wm[i][mm] = (i < 32) ? cw[i * 512 + oo * 16 + k0]
                         : cw[(i - 32) * 512 + oo * 16 + k0 + 8];
  }
  __syncthreads();

  float acc[2][8][4];   // [ol][k0][si]
#pragma unroll
  for (int ol = 0; ol < 2; ++ol) {
    float bo = cbias[mtp * 16 + wv * 2 + ol];
#pragma unroll
    for (int k0 = 0; k0 < 8; ++k0)
#pragma unroll
      for (int si = 0; si < 4; ++si) acc[ol][k0][si] = bo;
  }

  for (int c = 0; c < 32; ++c) {
    float xm1[4], x0[4];
#pragma unroll
    for (int si = 0; si < 4; ++si) {
      xm1[si] = xs[c][lane + si * 64 + 3];
      x0[si]  = xs[c][lane + si * 64 + 4];
    }
    float w0[16], w1[16];
#pragma unroll
    for (int q = 0; q < 4; ++q) {
      *(float4*)&w0[q * 4] = *(const float4*)&wm[c][wv * 16 + q * 4];
      *(float4*)&w1[q * 4] = *(const float4*)&wm[32 + c][wv * 16 + q * 4];
    }
#pragma unroll
    for (int ol = 0; ol < 2; ++ol)
#pragma unroll
      for (int k0 = 0; k0 < 8; ++k0)
#pragma unroll
        for (int si = 0; si < 4; ++si)
          acc[ol][k0][si] += x0[si] * w0[ol * 8 + k0] + xm1[si] * w1[ol * 8 + k0];
  }

#pragma unroll
  for (int ol = 0; ol < 2; ++ol) {
    float* ob = hout + ((size_t)b * 32 + mtp * 16 + wv * 2 + ol) * T;
#pragma unroll
    for (int si = 0; si < 4; ++si) {
      int tb = (s0base + lane + si * 64) * 8 - 4;
      if (tb >= 0 && tb < T)
        *(float4*)(ob + tb) = make_float4(acc[ol][0][si], acc[ol][1][si],
                                          acc[ol][2][si], acc[ol][3][si]);
      if (tb + 4 >= 0 && tb + 4 < T)
        *(float4*)(ob + tb + 4) = make_float4(acc[ol][4][si], acc[ol][5][si],
                                              acc[ol][6][si], acc[ol][7][si]);
    }
  }
}

// ---------------- kern head GEMM (round-0) ----------------
__global__ void __launch_bounds__(256, 3) kern_head(const float* __restrict__ kp_h,
                                                    const float* __restrict__ kw,
                                                    const float* __restrict__ kb,
                                                    const float* __restrict__ bias_w,
                                                    const float* __restrict__ bias_b,
                                                    float* __restrict__ kh,
                                                    float* __restrict__ bh, int layer) {
    const int bx = blockIdx.x, b = blockIdx.y;
    const bool isbias = (bx >= 192);
    const int tid = threadIdx.x, lane = tid & 63, wv = tid >> 6;
    __shared__ float xs[32][264];
    __shared__ float ws[96][36];

    int g = 0, oc0 = 0, ci = 0, kk = 0, ocb0 = 0;
    const float* wsrc;
    size_t wrow0;
    int wstride;
    if (!isbias) {
        g = bx >> 1; oc0 = (bx & 1) * 32;
        ci = g / 3; kk = g - ci * 3;
        wsrc = kw + (size_t)layer * KCL * 192;
        wrow0 = (size_t)((ci * 64 + oc0) * 3 + kk) * 192;
        wstride = 576;
    } else {
        ocb0 = (bx - 192) * 32;
        wsrc = bias_w;
        wrow0 = (size_t)ocb0 * 192;
        wstride = 192;
    }

    float acc[8][4];
#pragma unroll
    for (int oi = 0; oi < 8; ++oi) {
        float bv = isbias ? bias_b[ocb0 + wv * 8 + oi]
                          : kb[layer * KCL + (ci * 64 + oc0 + wv * 8 + oi) * 3 + kk];
#pragma unroll
        for (int si = 0; si < 4; ++si) acc[oi][si] = bv;
    }

    for (int half = 0; half < 2; ++half) {
        const int hc0 = half * 32;
        __syncthreads();
        for (int idx = tid; idx < 32 * 64; idx += 256) {
            int c = idx >> 6, q = idx & 63;
            *(float4*)&xs[c][4 + 4 * q] =
                *(const float4*)(kp_h + ((size_t)b * 64 + hc0 + c) * LL + 4 * q);
        }
        if (tid < 32) { xs[tid][3] = 0.f; xs[tid][260] = 0.f; }
        for (int idx = tid; idx < 3072; idx += 256) {
            int ocl = idx / 96, jj = idx - ocl * 96;
            ws[jj][ocl] = wsrc[wrow0 + (size_t)ocl * wstride + hc0 * 3 + jj];
        }
        __syncthreads();
        for (int c = 0; c < 32; ++c) {
#pragma unroll
            for (int t = 0; t < 3; ++t) {
                float wv8[8];
                *(float4*)&wv8[0] = *(const float4*)&ws[c * 3 + t][wv * 8];
                *(float4*)&wv8[4] = *(const float4*)&ws[c * 3 + t][wv * 8 + 4];
                float xv[4];
#pragma unroll
                for (int si = 0; si < 4; ++si) xv[si] = xs[c][lane + si * 64 + t + 3];
#pragma unroll
                for (int oi = 0; oi < 8; ++oi)
#pragma unroll
                    for (int si = 0; si < 4; ++si)
                        acc[oi][si] += wv8[oi] * xv[si];
            }
        }
    }

    if (!isbias) {
#pragma unroll
        for (int si = 0; si < 4; ++si) {
            int l = lane + si * 64;
            float* op = kh + ((size_t)b * LL + l) * KCL + g * 64 + oc0 + wv * 8;
            *(float4*)(op)     = make_float4(acc[0][si], acc[1][si], acc[2][si], acc[3][si]);
            *(float4*)(op + 4) = make_float4(acc[4][si], acc[5][si], acc[6][si], acc[7][si]);
        }
    } else {
#pragma unroll
        for (int oi = 0; oi < 8; ++oi) {
            float* op = bh + ((size_t)b * 256 + ocb0 + wv * 8 + oi) * LL;
#pragma unroll
            for (int si = 0; si < 4; ++si)
                op[lane + si * 64] = acc[oi][si];
        }
    }
}

// ---------------- fused dilated conv + LVC + gate + residual (round-0) ----------------
__global__ void __launch_bounds__(512, 4) layer_fused(
    const float* __restrict__ kh, const float* __restrict__ bh,
    const float* __restrict__ w, const float* __restrict__ bias,
    const float* __restrict__ hin, float* __restrict__ hout,
    int layer, int dil) {
    const int l = blockIdx.x, b = blockIdx.y;
    const int tid = threadIdx.x, lane = tid & 63, wv = tid >> 6;
    const int t0 = l * 256;
    __shared__ float xh[32][316];   // 40.4 KB
    __shared__ float ks[KCL];       // 24.6 KB
    __shared__ float ws[96][36];    // 13.8 KB

    const float* hb = hin + (size_t)b * 32 * T;
    for (int idx = tid; idx < 32 * 64; idx += 512) {
        int c = idx >> 6, q = idx & 63;
        float4 v = *(const float4*)(hb + (size_t)c * T + t0 + 4 * q);
        *(float4*)&xh[c][32 + 4 * q] = make_float4(lrelu_f(v.x), lrelu_f(v.y),
                                                   lrelu_f(v.z), lrelu_f(v.w));
    }
    for (int idx = tid; idx < 32 * 60; idx += 512) {
        int c = idx / 60, r = idx - c * 60;
        int jj = (r < 32) ? r : (256 + r);
        int t = t0 + jj - 32;
        xh[c][jj] = (t >= 0 && t < T) ? lrelu_f(hb[(size_t)c * T + t]) : 0.f;
    }
    {
        const float4* kp = (const float4*)(kh + ((size_t)b * LL + l) * KCL);
        float4* kd = (float4*)ks;
        for (int idx = tid; idx < KCL / 4; idx += 512) kd[idx] = kp[idx];
    }
    for (int idx = tid; idx < 3072; idx += 512) {
        int oc = idx / 96, ck = idx - oc * 96;
        ws[ck][oc] = w[oc * 96 + ck];
    }
    __syncthreads();

    const int oc4 = wv * 4;
    float yv[5][4];
    {
        float a[5][4];
#pragma unroll
        for (int oi = 0; oi < 4; ++oi) {
            float bv = bias[oc4 + oi];
#pragma unroll
            for (int si = 0; si < 5; ++si) a[si][oi] = bv;
        }
        for (int c = 0; c < 32; ++c) {
#pragma unroll
            for (int k = 0; k < 3; ++k) {
                float4 wq = *(const float4*)&ws[c * 3 + k][oc4];
                float xv[5];
#pragma unroll
                for (int si = 0; si < 5; ++si) {
                    int col = lane + si * 64;
                    int colc = (col < 258) ? col : 257;
                    xv[si] = xh[c][colc + 31 + (k - 1) * dil];
                }
#pragma unroll
                for (int si = 0; si < 5; ++si) {
                    a[si][0] += xv[si] * wq.x;
                    a[si][1] += xv[si] * wq.y;
                    a[si][2] += xv[si] * wq.z;
                    a[si][3] += xv[si] * wq.w;
                }
            }
        }
#pragma unroll
        for (int si = 0; si < 5; ++si) {
            int t = t0 - 1 + lane + si * 64;
            bool tval = (t >= 0 && t < T);
#pragma unroll
            for (int oi = 0; oi < 4; ++oi)
                yv[si][oi] = tval ? lrelu_f(a[si][oi]) : 0.f;
        }
    }
    __syncthreads();

#pragma unroll
    for (int si = 0; si < 5; ++si) {
        int col = lane + si * 64;
        if (col < 258) {
#pragma unroll
            for (int oi = 0; oi < 4; ++oi) xh[oc4 + oi][col + 31] = yv[si][oi];
        }
    }
    __syncthreads();

    const int oc8 = (wv & 3) * 8;
    const int sh  = wv >> 2;
    float acc_a[8][2], acc_g[8][2];
#pragma unroll
    for (int oi = 0; oi < 8; ++oi) {
        float ba = bh[((size_t)b * 256 + layer * 64 + oc8 + oi) * LL + l];
        float bg = bh[((size_t)b * 256 + layer * 64 + 32 + oc8 + oi) * LL + l];
#pragma unroll
        for (int si = 0; si < 2; ++si) { acc_a[oi][si] = ba; acc_g[oi][si] = bg; }
    }

    for (int c = 0; c < 32; ++c) {
#pragma unroll
        for (int k = 0; k < 3; ++k) {
            const float* kr = ks + (c * 3 + k) * 64;
            float wa[8], wg[8];
            *(float4*)&wa[0] = *(const float4*)(kr + oc8);
            *(float4*)&wa[4] = *(const float4*)(kr + oc8 + 4);
            *(float4*)&wg[0] = *(const float4*)(kr + 32 + oc8);
            *(float4*)&wg[4] = *(const float4*)(kr + 32 + oc8 + 4);
            float xv2[2];
#pragma unroll
            for (int si = 0; si < 2; ++si) {
                int s = lane + (sh * 2 + si) * 64;
                xv2[si] = xh[c][s + k + 31];
            }
#pragma unroll
            for (int oi = 0; oi < 8; ++oi)
#pragma unroll
                for (int si = 0; si < 2; ++si) {
                    acc_a[oi][si] += wa[oi] * xv2[si];
                    acc_g[oi][si] += wg[oi] * xv2[si];
                }
        }
    }

#pragma unroll
    for (int oi = 0; oi < 8; ++oi) {
        const float* hip = hin + ((size_t)b * 32 + oc8 + oi) * T + t0;
        float* hop = hout + ((size_t)b * 32 + oc8 + oi) * T + t0;
#pragma unroll
        for (int si = 0; si < 2; ++si) {
            int s = lane + (sh * 2 + si) * 64;
            float a = acc_a[oi][si], g = acc_g[oi][si];
            float sg = 1.f / (1.f + __expf(-a));
            float th = tanhf(g);
            hop[s] = sg * th + hip[s];
        }
    }
}

extern "C" void kernel_launch(void* const* d_in, const int* in_sizes, int n_in,
                              void* d_out, int out_size, void* d_ws, size_t ws_size,
                              hipStream_t stream) {
    const float* hidden  = (const float*)d_in[0];
    const float* spec    = (const float*)d_in[1];
    const float* convt_w = (const float*)d_in[2];
    const float* convt_b = (const float*)d_in[3];
    const float* kp_in_w = (const float*)d_in[4];
    const float* kp_in_b = (const float*)d_in[5];
    const float* rb_w1   = (const float*)d_in[6];
    const float* rb_b1   = (const float*)d_in[7];
    const float* rb_w2   = (const float*)d_in[8];
    const float* rb_b2   = (const float*)d_in[9];
    const float* kern_w  = (const float*)d_in[10];
    const float* kern_b  = (const float*)d_in[11];
    const float* bias_w  = (const float*)d_in[12];
    const float* bias_b  = (const float*)d_in[13];
    const float* lvc_w   = (const float*)d_in[14];
    const float* lvc_b   = (const float*)d_in[15];

    float* wsp = (float*)d_ws;
    float* h_ws     = wsp;                                 // NB*32*T
    float* kh_layer = h_ws + (size_t)NB * 32 * T;          // NB*LL*KCL
    float* bh       = kh_layer + (size_t)NB * LL * KCL;    // NB*256*LL
    float* kp_h     = bh + (size_t)NB * 256 * LL;          // NB*64*LL
    float* trb      = kp_h + (size_t)NB * 64 * LL;         // 6*192*64 = 73728
    float* tkpin    = trb + (size_t)6 * 192 * 64;          // 500*64   = 32000

    float* h0 = (float*)d_out;
    float* h1 = h_ws;

    // 0) one-time weight transposes for trunk
    prep1<<<dim3(7), 256, 0, stream>>>(rb_w1, rb_w2, kp_in_w, trb, tkpin);

    // 1) merged trunk (blocks 0..63, scheduled first) + convt (blocks 64..327)
    phase1<<<dim3(328), 512, 0, stream>>>(hidden, convt_w, convt_b, h0,
                                          spec, tkpin, kp_in_b,
                                          trb, rb_b1, rb_b2, kp_h);

    static const int dil[4] = {1, 3, 9, 27};
    float* hin = h0;
    float* hout = h1;
    for (int layer = 0; layer < 4; ++layer) {
        kern_head<<<dim3(layer == 0 ? 200 : 192, NB), 256, 0, stream>>>(
            kp_h, kern_w, kern_b, bias_w, bias_b, kh_layer, bh, layer);
        layer_fused<<<dim3(LL, NB), 512, 0, stream>>>(
            kh_layer, bh, lvc_w + (size_t)layer * 32 * 32 * 3, lvc_b + layer * 32,
            hin, hout, layer, dil[layer]);
        float* tmp = hin; hin = hout; hout = tmp;
    }
    // after 4 swaps the final output landed in h0 = d_out
}